// Round 4
// baseline (546.228 us; speedup 1.0000x reference)
//
#include <hip/hip_runtime.h>
#include <stdint.h>

// WeightedSumSessEmbedding via counting-sort sequentialization.
// Random 256B gathers plateau ~650 GB/s (R1-R3 all ~330us regardless of MLP).
// Plan: sort nnz by col into 128-row buckets; stream the ENTIRE emb table
// sequentially (256 MB) window-by-window into LDS; write weighted rows to
// wscratch[j] (j = original row-sorted index); then segment-sum wscratch
// sequentially per session. Only random phase = full-line 256B writes.
// No float atomics. Output bitwise deterministic (j-ordered everywhere).

#define RPB      128          // rows per bucket -> 32 KB LDS window
#define LOG_RPB  7

__global__ __launch_bounds__(256) void k1_rowptr_hist(
    const int* __restrict__ row_idx,
    const int* __restrict__ col_idx,
    int* __restrict__ row_ptr,       // [num_sess+1], every entry written
    int* __restrict__ hist,          // [nb], pre-zeroed
    int nnz, int num_sess)
{
    int j = blockIdx.x * 256 + threadIdx.x;
    if (j >= nnz) return;
    int r = row_idx[j];
    if (j == 0) {
        for (int s = 0; s <= r; ++s) row_ptr[s] = 0;
    } else {
        int rp = row_idx[j - 1];
        for (int s = rp + 1; s <= r; ++s) row_ptr[s] = j;
    }
    if (j == nnz - 1) {
        for (int s = r + 1; s <= num_sess; ++s) row_ptr[s] = nnz;
    }
    atomicAdd(&hist[col_idx[j] >> LOG_RPB], 1);   // ~100/bin, low contention
}

// single block, 1024 threads, handles nb <= 8192 bins
__global__ __launch_bounds__(1024) void k2_scan(
    const int* __restrict__ hist,
    int* __restrict__ bstart,        // [nb+1]
    int* __restrict__ cursor,        // [nb]
    int nb)
{
    __shared__ int tsum[1024];
    int t = threadIdx.x;
    int loc[8];
    int base = t * 8;
    int s = 0;
    #pragma unroll
    for (int k = 0; k < 8; ++k) {
        int b = base + k;
        int v = (b < nb) ? hist[b] : 0;
        loc[k] = s;
        s += v;
    }
    tsum[t] = s;
    __syncthreads();
    for (int off = 1; off < 1024; off <<= 1) {
        int v = (t >= off) ? tsum[t - off] : 0;
        __syncthreads();
        tsum[t] += v;
        __syncthreads();
    }
    int tbase = (t == 0) ? 0 : tsum[t - 1];
    #pragma unroll
    for (int k = 0; k < 8; ++k) {
        int b = base + k;
        if (b < nb) {
            int st = tbase + loc[k];
            bstart[b] = st;
            cursor[b] = st;
        }
    }
    if (t == 1023) bstart[nb] = tsum[1023];
}

__global__ __launch_bounds__(256) void k3_scatter(
    const int*   __restrict__ col_idx,
    const float* __restrict__ data,
    int*    __restrict__ cursor,     // init = bstart (from k2)
    float2* __restrict__ colw,       // [nnz] {col-as-bits, weight}
    int*    __restrict__ jidx,       // [nnz] original index
    int nnz)
{
    int j = blockIdx.x * 256 + threadIdx.x;
    if (j >= nnz) return;
    int   c = col_idx[j];
    float w = data[j];
    int pos = atomicAdd(&cursor[c >> LOG_RPB], 1);
    colw[pos] = make_float2(__int_as_float(c), w);
    jidx[pos] = j;
}

// one workgroup per bucket: stream 32KB emb window seq -> LDS, then for each
// nnz in bucket write weighted row to wscratch[j] (full-line 256B store).
__global__ __launch_bounds__(256) void k4_materialize(
    const float4* __restrict__ emb4,     // [items*16]
    const float2* __restrict__ colw,
    const int*    __restrict__ jidx,
    const int*    __restrict__ bstart,
    float*        __restrict__ wscratch, // [nnz*64]
    int items)
{
    __shared__ float4 win[RPB * 16];     // 32 KB
    const int b = blockIdx.x;
    const int t = threadIdx.x;

    const size_t gbase = (size_t)b * (RPB * 16);
    const size_t glim  = (size_t)items * 16;
    #pragma unroll
    for (int k = 0; k < 8; ++k) {
        int li = t + k * 256;            // 0..2047
        size_t gi = gbase + li;
        if (gi < glim) win[li] = emb4[gi];
    }
    __syncthreads();

    const float* winf = (const float*)win;
    const int bs = bstart[b], be = bstart[b + 1];
    const int wv = t >> 6, lane = t & 63;

    for (int i = bs + wv; i < be; i += 4) {
        float2 cw = colw[i];             // wave-broadcast load
        int    c  = __float_as_int(cw.x);
        int    j  = jidx[i];
        float  v  = winf[(c & (RPB - 1)) * 64 + lane];  // 2-way bank alias: free
        wscratch[(size_t)j * 64 + lane] = cw.y * v;     // 256B contiguous store
    }
}

// one wave per session: sequential segment sum of wscratch rows.
__global__ __launch_bounds__(256, 8) void k5_segsum(
    const int*   __restrict__ row_ptr,
    const float* __restrict__ wscratch,
    float*       __restrict__ out,
    int num_sess)
{
    const int wv   = threadIdx.x >> 6;
    const int lane = threadIdx.x & 63;
    const int sess = (blockIdx.x << 2) + wv;
    if (sess >= num_sess) return;

    const int s = row_ptr[sess], e = row_ptr[sess + 1];
    const int n = e - s;
    const float* p = wscratch + (size_t)s * 64 + lane;

    float a0 = 0.f, a1 = 0.f, a2 = 0.f, a3 = 0.f;
    int k = 0;
    for (; k + 4 <= n; k += 4) {
        a0 += p[(size_t)(k + 0) * 64];
        a1 += p[(size_t)(k + 1) * 64];
        a2 += p[(size_t)(k + 2) * 64];
        a3 += p[(size_t)(k + 3) * 64];
    }
    for (; k < n; ++k) a0 += p[(size_t)k * 64];

    out[(size_t)sess * 64 + lane] = (a0 + a1) + (a2 + a3);
}

static inline char* align256(char* p) {
    return (char*)(((uintptr_t)p + 255) & ~(uintptr_t)255);
}

extern "C" void kernel_launch(void* const* d_in, const int* in_sizes, int n_in,
                              void* d_out, int out_size, void* d_ws, size_t ws_size,
                              hipStream_t stream) {
    const int*   row_idx = (const int*)  d_in[0];
    const int*   col_idx = (const int*)  d_in[1];
    const float* data    = (const float*)d_in[2];
    const float* emb     = (const float*)d_in[4];

    const int nnz      = in_sizes[0];
    const int num_sess = out_size / 64;        // EMB_DIM = 64
    const int items    = in_sizes[4] / 64;     // 1,000,000
    const int nb       = (items + RPB - 1) >> LOG_RPB;   // 7813

    // workspace carve (~220 MB, ws is ~1 GB)
    char* p = (char*)d_ws;
    float* wscratch = (float*)p;            p += (size_t)nnz * 64 * sizeof(float);
    p = align256(p);
    int* row_ptr = (int*)p;                 p += (size_t)(num_sess + 1) * sizeof(int);
    p = align256(p);
    int* hist = (int*)p;                    p += (size_t)nb * sizeof(int);
    p = align256(p);
    int* bstart = (int*)p;                  p += (size_t)(nb + 1) * sizeof(int);
    p = align256(p);
    int* cursor = (int*)p;                  p += (size_t)nb * sizeof(int);
    p = align256(p);
    float2* colw = (float2*)p;              p += (size_t)nnz * sizeof(float2);
    p = align256(p);
    int* jidx = (int*)p;                    p += (size_t)nnz * sizeof(int);

    hipMemsetAsync(hist, 0, (size_t)nb * sizeof(int), stream);

    const int jblocks = (nnz + 255) / 256;
    k1_rowptr_hist<<<jblocks, 256, 0, stream>>>(
        row_idx, col_idx, row_ptr, hist, nnz, num_sess);

    k2_scan<<<1, 1024, 0, stream>>>(hist, bstart, cursor, nb);

    k3_scatter<<<jblocks, 256, 0, stream>>>(
        col_idx, data, cursor, colw, jidx, nnz);

    k4_materialize<<<nb, 256, 0, stream>>>(
        (const float4*)emb, colw, jidx, bstart, wscratch, items);

    k5_segsum<<<(num_sess + 3) / 4, 256, 0, stream>>>(
        row_ptr, wscratch, (float*)d_out, num_sess);
}

// Round 5
// 534.689 us; speedup vs baseline: 1.0216x; 1.0216x over previous
//
#include <hip/hip_runtime.h>
#include <stdint.h>

// WeightedSumSessEmbedding: out[s,:] += data[j] * emb[col_idx[j],:]
// R1-R4 lesson: random 256B granules over a >100MB HBM footprint cap at
// ~650 GB/s in EITHER direction (L3 is flushed each iter by the 1GB ws
// poison). Only fix: shrink the random footprint. Pipeline:
//   k1 hist -> k2 scan -> k3 scatter records {col,sess,w} into col-bucket
//   order -> k4 streams the ENTIRE emb table sequentially (32KB LDS
//   windows), stages records in LDS, and atomicAdds w*row into out (4MB,
//   cache-resident). Random traffic = 52M x 4B atomics into 4MB, not
//   210MB x 256B scatter. Atomics are fire-and-forget (no return value).

#define RPB       128         // rows per bucket -> 32 KB LDS window
#define LOG_RPB   7
#define REC_CHUNK 256         // records staged per LDS pass (4 KB)

__global__ __launch_bounds__(256) void k1_hist(
    const int* __restrict__ col_idx,
    int*       __restrict__ hist,    // [nb], pre-zeroed
    int nnz)
{
    int j = blockIdx.x * 256 + threadIdx.x;
    if (j < nnz) atomicAdd(&hist[col_idx[j] >> LOG_RPB], 1);
}

// single block, 1024 threads, handles nb <= 8192 bins
__global__ __launch_bounds__(1024) void k2_scan(
    const int* __restrict__ hist,
    int* __restrict__ bstart,        // [nb+1]
    int* __restrict__ cursor,        // [nb]
    int nb)
{
    __shared__ int tsum[1024];
    int t = threadIdx.x;
    int loc[8];
    int base = t * 8;
    int s = 0;
    #pragma unroll
    for (int k = 0; k < 8; ++k) {
        int b = base + k;
        int v = (b < nb) ? hist[b] : 0;
        loc[k] = s;
        s += v;
    }
    tsum[t] = s;
    __syncthreads();
    for (int off = 1; off < 1024; off <<= 1) {
        int v = (t >= off) ? tsum[t - off] : 0;
        __syncthreads();
        tsum[t] += v;
        __syncthreads();
    }
    int tbase = (t == 0) ? 0 : tsum[t - 1];
    #pragma unroll
    for (int k = 0; k < 8; ++k) {
        int b = base + k;
        if (b < nb) {
            int st = tbase + loc[k];
            bstart[b] = st;
            cursor[b] = st;
        }
    }
    if (t == 1023) bstart[nb] = tsum[1023];
}

__global__ __launch_bounds__(256) void k3_scatter(
    const int*   __restrict__ col_idx,
    const int*   __restrict__ row_idx,
    const float* __restrict__ data,
    int*  __restrict__ cursor,       // init = bstart (from k2)
    int4* __restrict__ recs,         // [nnz] {col, sess, w_bits, 0}
    int nnz)
{
    int j = blockIdx.x * 256 + threadIdx.x;
    if (j >= nnz) return;
    int c = col_idx[j];
    int pos = atomicAdd(&cursor[c >> LOG_RPB], 1);
    recs[pos] = make_int4(c, row_idx[j], __float_as_int(data[j]), 0);
}

// one workgroup per bucket: stream 32KB emb window -> LDS, stage records
// in LDS chunks, atomicAdd weighted rows into out (4MB, cache-resident).
__global__ __launch_bounds__(256) void k4_apply(
    const float4* __restrict__ emb4,     // [items*16]
    const int4*   __restrict__ recs,
    const int*    __restrict__ bstart,
    float*        __restrict__ out,      // [num_sess*64], pre-zeroed
    int items)
{
    __shared__ float4 win[RPB * 16];     // 32 KB
    __shared__ int4   rc[REC_CHUNK];     // 4 KB
    const int b = blockIdx.x;
    const int t = threadIdx.x;

    const size_t gbase = (size_t)b * (RPB * 16);
    const size_t glim  = (size_t)items * 16;
    #pragma unroll
    for (int k = 0; k < 8; ++k) {
        int li = t + k * 256;            // 0..2047
        size_t gi = gbase + li;
        if (gi < glim) win[li] = emb4[gi];
    }

    const int bs = bstart[b], be = bstart[b + 1];
    const float* winf = (const float*)win;
    const int wv = t >> 6, lane = t & 63;

    for (int cs = bs; cs < be; cs += REC_CHUNK) {
        int cnt = min(REC_CHUNK, be - cs);
        __syncthreads();                 // window ready / rc free
        if (t < cnt) rc[t] = recs[cs + t];
        __syncthreads();
        for (int r = wv; r < cnt; r += 4) {
            int4  rec = rc[r];           // LDS broadcast
            float w   = __int_as_float(rec.z);
            float v   = winf[(rec.x & (RPB - 1)) * 64 + lane]; // 2-way alias: free
            atomicAdd(&out[(size_t)rec.y * 64 + lane], w * v); // fire-and-forget
        }
    }
}

static inline char* align256(char* p) {
    return (char*)(((uintptr_t)p + 255) & ~(uintptr_t)255);
}

extern "C" void kernel_launch(void* const* d_in, const int* in_sizes, int n_in,
                              void* d_out, int out_size, void* d_ws, size_t ws_size,
                              hipStream_t stream) {
    const int*   row_idx = (const int*)  d_in[0];
    const int*   col_idx = (const int*)  d_in[1];
    const float* data    = (const float*)d_in[2];
    const float* emb     = (const float*)d_in[4];

    const int nnz   = in_sizes[0];
    const int items = in_sizes[4] / 64;                 // 1,000,000
    const int nb    = (items + RPB - 1) >> LOG_RPB;     // 7813

    // workspace carve
    char* p = (char*)d_ws;
    int* hist = (int*)p;     p += (size_t)nb * sizeof(int);        p = align256(p);
    int* bstart = (int*)p;   p += (size_t)(nb + 1) * sizeof(int);  p = align256(p);
    int* cursor = (int*)p;   p += (size_t)nb * sizeof(int);        p = align256(p);
    int4* recs = (int4*)p;   p += (size_t)nnz * sizeof(int4);

    hipMemsetAsync(hist, 0, (size_t)nb * sizeof(int), stream);
    hipMemsetAsync(d_out, 0, (size_t)out_size * sizeof(float), stream);

    const int jblocks = (nnz + 255) / 256;
    k1_hist<<<jblocks, 256, 0, stream>>>(col_idx, hist, nnz);
    k2_scan<<<1, 1024, 0, stream>>>(hist, bstart, cursor, nb);
    k3_scatter<<<jblocks, 256, 0, stream>>>(
        col_idx, row_idx, data, cursor, recs, nnz);
    k4_apply<<<nb, 256, 0, stream>>>(
        (const float4*)emb, recs, bstart, (float*)d_out, items);
}